// Round 3
// baseline (3346.742 us; speedup 1.0000x reference)
//
#include <hip/hip_runtime.h>
#include <hip/hip_bf16.h>

#define N_NODES 50000
#define N_EDGES 1000000
#define HID 128
#define NCLS 27   // C+1

// ---------------------------------------------------------------------------
// Kernel 1: per-node embeddings.
// subj[n] = node_cat @ subj_W + subj_b ; obj[n] = node_cat @ obj_W + obj_b
// node_cat = [dim_e(32) | orient_e(32)]
// block = 256 threads, 32 nodes per block.
// ---------------------------------------------------------------------------
__global__ __launch_bounds__(256) void node_embed_kernel(
    const int* __restrict__ orientation,
    const float* __restrict__ dimension,
    const float* __restrict__ orient_table,
    const float* __restrict__ size_W,
    const float* __restrict__ size_b,
    const float* __restrict__ subj_W,
    const float* __restrict__ subj_b,
    const float* __restrict__ obj_W,
    const float* __restrict__ obj_b,
    float* __restrict__ subj_out,
    float* __restrict__ obj_out)
{
    __shared__ float cat[32][64];
    const int t = threadIdx.x;
    const int nb = blockIdx.x * 32;

    // stage node_cat[32][64]
    for (int idx = t; idx < 32 * 64; idx += 256) {
        const int nl = idx >> 6;
        const int j  = idx & 63;
        const int n  = nb + nl;
        float v = 0.f;
        if (n < N_NODES) {
            if (j < 32) {
                v = size_b[j];
                v += dimension[n * 3 + 0] * size_W[0 * 32 + j];
                v += dimension[n * 3 + 1] * size_W[1 * 32 + j];
                v += dimension[n * 3 + 2] * size_W[2 * 32 + j];
            } else {
                v = orient_table[orientation[n] * 32 + (j - 32)];
            }
        }
        cat[nl][j] = v;
    }
    __syncthreads();

    // 64 col-groups of 4 cols (256 virtual cols = subj 128 | obj 128),
    // 4 node-groups of 8 nodes.
    const int cwg = t & 63;
    const int ng  = t >> 6;
    const int c0  = cwg * 4;
    const bool is_subj = (c0 < 128);
    const float* W = is_subj ? subj_W : obj_W;
    const float* B = is_subj ? subj_b : obj_b;
    float* outp    = is_subj ? subj_out : obj_out;
    const int cc   = is_subj ? c0 : (c0 - 128);

    float acc[8][4];
#pragma unroll
    for (int i = 0; i < 8; ++i)
#pragma unroll
        for (int j = 0; j < 4; ++j) acc[i][j] = 0.f;

    for (int k = 0; k < 64; ++k) {
        const float4 w = *(const float4*)&W[k * 128 + cc];
#pragma unroll
        for (int i = 0; i < 8; ++i) {
            const float a = cat[ng * 8 + i][k];
            acc[i][0] += a * w.x; acc[i][1] += a * w.y;
            acc[i][2] += a * w.z; acc[i][3] += a * w.w;
        }
    }

    const float4 bias = *(const float4*)&B[cc];
#pragma unroll
    for (int i = 0; i < 8; ++i) {
        const int n = nb + ng * 8 + i;
        if (n < N_NODES) {
            float4 r;
            r.x = acc[i][0] + bias.x; r.y = acc[i][1] + bias.y;
            r.z = acc[i][2] + bias.z; r.w = acc[i][3] + bias.w;
            *(float4*)&outp[(size_t)n * HID + cc] = r;
        }
    }
}

// ---------------------------------------------------------------------------
// Kernel 2: fused per-edge MLP. 64 edges per block, 256 threads (4 waves).
// LDS union (65536 B):
//   phase A (GEMM1): A_tile[64][132] fp32 at [0, 33792) floats [0,8448)
//                    scratch: srcs[64] int @ floats 8448, dsts[64] @ 8512,
//                             diff[64][4] @ 8576
//   phase B: H1[64][256] fp32 = entire 16384-float region
//   phase C: H2[64][128] fp32 at [0, 8192)
// ---------------------------------------------------------------------------
__global__ __launch_bounds__(256) void edge_mlp_kernel(
    const float* __restrict__ location,
    const int* __restrict__ src,
    const int* __restrict__ dst,
    const float* __restrict__ subj_e,
    const float* __restrict__ obj_e,
    const float* __restrict__ trans_W,
    const float* __restrict__ trans_b,
    const float* __restrict__ W1, const float* __restrict__ b1,
    const float* __restrict__ W2, const float* __restrict__ b2,
    const float* __restrict__ W3, const float* __restrict__ b3,
    float* __restrict__ out)
{
    __shared__ float smem[16384];   // 64 KB

    const int t  = threadIdx.x;
    const int eb = blockIdx.x * 64;

    int*   srcs = (int*)(smem + 8448);
    int*   dsts = (int*)(smem + 8512);
    float* diff = smem + 8576;

    if (t < 64) {
        const int s = src[eb + t];
        const int d = dst[eb + t];
        srcs[t] = s;
        dsts[t] = d;
        diff[t * 4 + 0] = location[s * 3 + 0] - location[d * 3 + 0];
        diff[t * 4 + 1] = location[s * 3 + 1] - location[d * 3 + 1];
        diff[t * 4 + 2] = location[s * 3 + 2] - location[d * 3 + 2];
    }
    __syncthreads();

    const int cg = t & 31;   // 32 col-groups of 8 (GEMM1: 256 cols)
    const int eg = t >> 5;   // 8 edge-groups of 8
    const int e4 = t >> 2;   // staging: edge index
    const int fq = t & 3;    // staging: float4 slot

    float acc1[8][8];
#pragma unroll
    for (int i = 0; i < 8; ++i)
#pragma unroll
        for (int j = 0; j < 8; ++j) acc1[i][j] = 0.f;

    // ---- GEMM1: H1 = relu(edge_in[64][384] @ W1[384][256] + b1) ----
    for (int tile = 0; tile < 3; ++tile) {
        if (tile != 1) {
            const float* tab = (tile == 0) ? subj_e : obj_e;
            const int*  idxs = (tile == 0) ? srcs : dsts;
            const int row = idxs[e4];
            const float* rp = tab + (size_t)row * HID;
#pragma unroll
            for (int i = 0; i < 8; ++i) {
                const int f = fq + i * 4;       // float4 index 0..31
                const float4 v = *(const float4*)&rp[f * 4];
                *(float4*)&smem[e4 * 132 + f * 4] = v;
            }
        } else {
            const float d0 = diff[e4 * 4 + 0];
            const float d1 = diff[e4 * 4 + 1];
            const float d2 = diff[e4 * 4 + 2];
#pragma unroll
            for (int i = 0; i < 8; ++i) {
                const int c = (fq + i * 4) * 4;
                const float4 w0 = *(const float4*)&trans_W[0 * HID + c];
                const float4 w1 = *(const float4*)&trans_W[1 * HID + c];
                const float4 w2 = *(const float4*)&trans_W[2 * HID + c];
                const float4 bb = *(const float4*)&trans_b[c];
                float4 r;
                r.x = d0 * w0.x + d1 * w1.x + d2 * w2.x + bb.x;
                r.y = d0 * w0.y + d1 * w1.y + d2 * w2.y + bb.y;
                r.z = d0 * w0.z + d1 * w1.z + d2 * w2.z + bb.z;
                r.w = d0 * w0.w + d1 * w1.w + d2 * w2.w + bb.w;
                *(float4*)&smem[e4 * 132 + c] = r;
            }
        }
        __syncthreads();

        const float* Wrow = W1 + (size_t)(tile * 128) * 256;
        for (int kk = 0; kk < 128; kk += 4) {
            float4 av[8];
#pragma unroll
            for (int i = 0; i < 8; ++i)
                av[i] = *(const float4*)&smem[(eg * 8 + i) * 132 + kk];
#pragma unroll
            for (int u = 0; u < 4; ++u) {
                const float4 w0 = *(const float4*)&Wrow[(kk + u) * 256 + cg * 8];
                const float4 w1 = *(const float4*)&Wrow[(kk + u) * 256 + cg * 8 + 4];
#pragma unroll
                for (int i = 0; i < 8; ++i) {
                    const float a = (u == 0) ? av[i].x : (u == 1) ? av[i].y
                                  : (u == 2) ? av[i].z : av[i].w;
                    acc1[i][0] += a * w0.x; acc1[i][1] += a * w0.y;
                    acc1[i][2] += a * w0.z; acc1[i][3] += a * w0.w;
                    acc1[i][4] += a * w1.x; acc1[i][5] += a * w1.y;
                    acc1[i][6] += a * w1.z; acc1[i][7] += a * w1.w;
                }
            }
        }
        __syncthreads();
    }

    // write H1 = relu(acc1 + b1) over the whole LDS region
    {
        const float4 bb0 = *(const float4*)&b1[cg * 8];
        const float4 bb1 = *(const float4*)&b1[cg * 8 + 4];
#pragma unroll
        for (int i = 0; i < 8; ++i) {
            float4 r0, r1;
            r0.x = fmaxf(acc1[i][0] + bb0.x, 0.f);
            r0.y = fmaxf(acc1[i][1] + bb0.y, 0.f);
            r0.z = fmaxf(acc1[i][2] + bb0.z, 0.f);
            r0.w = fmaxf(acc1[i][3] + bb0.w, 0.f);
            r1.x = fmaxf(acc1[i][4] + bb1.x, 0.f);
            r1.y = fmaxf(acc1[i][5] + bb1.y, 0.f);
            r1.z = fmaxf(acc1[i][6] + bb1.z, 0.f);
            r1.w = fmaxf(acc1[i][7] + bb1.w, 0.f);
            *(float4*)&smem[(eg * 8 + i) * 256 + cg * 8]     = r0;
            *(float4*)&smem[(eg * 8 + i) * 256 + cg * 8 + 4] = r1;
        }
    }
    __syncthreads();

    // ---- GEMM2: H2 = relu(H1[64][256] @ W2[256][128] + b2) ----
    float acc2[8][4];
#pragma unroll
    for (int i = 0; i < 8; ++i)
#pragma unroll
        for (int j = 0; j < 4; ++j) acc2[i][j] = 0.f;

    for (int kk = 0; kk < 256; kk += 4) {
        float4 av[8];
#pragma unroll
        for (int i = 0; i < 8; ++i)
            av[i] = *(const float4*)&smem[(eg * 8 + i) * 256 + kk];
#pragma unroll
        for (int u = 0; u < 4; ++u) {
            const float4 w = *(const float4*)&W2[(kk + u) * 128 + cg * 4];
#pragma unroll
            for (int i = 0; i < 8; ++i) {
                const float a = (u == 0) ? av[i].x : (u == 1) ? av[i].y
                              : (u == 2) ? av[i].z : av[i].w;
                acc2[i][0] += a * w.x; acc2[i][1] += a * w.y;
                acc2[i][2] += a * w.z; acc2[i][3] += a * w.w;
            }
        }
    }
    __syncthreads();

    // write H2 = relu(acc2 + b2) at [0, 8192)
    {
        const float4 bb = *(const float4*)&b2[cg * 4];
#pragma unroll
        for (int i = 0; i < 8; ++i) {
            float4 r;
            r.x = fmaxf(acc2[i][0] + bb.x, 0.f);
            r.y = fmaxf(acc2[i][1] + bb.y, 0.f);
            r.z = fmaxf(acc2[i][2] + bb.z, 0.f);
            r.w = fmaxf(acc2[i][3] + bb.w, 0.f);
            *(float4*)&smem[(eg * 8 + i) * 128 + cg * 4] = r;
        }
    }
    __syncthreads();

    // ---- GEMM3: scores = H2[64][128] @ W3[128][27] + b3 ----
    const int c   = cg;             // lanes 0..26 active for store
    const int cc3 = (c < NCLS) ? c : (NCLS - 1);
    float acc3[8];
#pragma unroll
    for (int i = 0; i < 8; ++i) acc3[i] = 0.f;

    for (int kk = 0; kk < 128; kk += 4) {
        float4 av[8];
#pragma unroll
        for (int i = 0; i < 8; ++i)
            av[i] = *(const float4*)&smem[(eg * 8 + i) * 128 + kk];
#pragma unroll
        for (int u = 0; u < 4; ++u) {
            const float w = W3[(kk + u) * NCLS + cc3];
#pragma unroll
            for (int i = 0; i < 8; ++i) {
                const float a = (u == 0) ? av[i].x : (u == 1) ? av[i].y
                              : (u == 2) ? av[i].z : av[i].w;
                acc3[i] += a * w;
            }
        }
    }

    if (c < NCLS) {
        const float bw = b3[c];
#pragma unroll
        for (int i = 0; i < 8; ++i) {
            const int e = eb + eg * 8 + i;
            out[(size_t)e * NCLS + c] = acc3[i] + bw;
        }
    }
}

// ---------------------------------------------------------------------------
// Kernel 3: targets -> float copy into d_out tail
// ---------------------------------------------------------------------------
__global__ __launch_bounds__(256) void targets_copy_kernel(
    const int* __restrict__ targets, float* __restrict__ out_tail, int n)
{
    const int i = blockIdx.x * blockDim.x + threadIdx.x;
    if (i < n) out_tail[i] = (float)targets[i];
}

// ---------------------------------------------------------------------------
extern "C" void kernel_launch(void* const* d_in, const int* in_sizes, int n_in,
                              void* d_out, int out_size, void* d_ws, size_t ws_size,
                              hipStream_t stream) {
    const int*   orientation  = (const int*)  d_in[0];
    const float* dimension    = (const float*)d_in[1];
    const float* location     = (const float*)d_in[2];
    const int*   src          = (const int*)  d_in[3];
    const int*   dst          = (const int*)  d_in[4];
    const int*   targets      = (const int*)  d_in[5];
    const float* orient_table = (const float*)d_in[6];
    const float* size_W       = (const float*)d_in[7];
    const float* size_b       = (const float*)d_in[8];
    const float* subj_W       = (const float*)d_in[9];
    const float* subj_b       = (const float*)d_in[10];
    const float* obj_W        = (const float*)d_in[11];
    const float* obj_b        = (const float*)d_in[12];
    const float* trans_W      = (const float*)d_in[13];
    const float* trans_b      = (const float*)d_in[14];
    const float* W1           = (const float*)d_in[15];
    const float* b1           = (const float*)d_in[16];
    const float* W2           = (const float*)d_in[17];
    const float* b2           = (const float*)d_in[18];
    const float* W3           = (const float*)d_in[19];
    const float* b3           = (const float*)d_in[20];

    float* subj_e = (float*)d_ws;
    float* obj_e  = subj_e + (size_t)N_NODES * HID;
    float* out    = (float*)d_out;

    node_embed_kernel<<<(N_NODES + 31) / 32, 256, 0, stream>>>(
        orientation, dimension, orient_table, size_W, size_b,
        subj_W, subj_b, obj_W, obj_b, subj_e, obj_e);

    edge_mlp_kernel<<<N_EDGES / 64, 256, 0, stream>>>(
        location, src, dst, subj_e, obj_e, trans_W, trans_b,
        W1, b1, W2, b2, W3, b3, out);

    targets_copy_kernel<<<(N_EDGES + 255) / 256, 256, 0, stream>>>(
        targets, out + (size_t)N_EDGES * NCLS, N_EDGES);
}

// Round 4
// 522.891 us; speedup vs baseline: 6.4005x; 6.4005x over previous
//
#include <hip/hip_runtime.h>
#include <hip/hip_bf16.h>

#define N_NODES 50000
#define N_EDGES 1000000
#define NCLS 27   // C+1

typedef short s8v __attribute__((ext_vector_type(8)));   // 8 x bf16 bits (4 VGPR)
typedef float f4v __attribute__((ext_vector_type(4)));   // MFMA acc

__device__ __forceinline__ ushort f2bf(float f) {
    __hip_bfloat16 h = __float2bfloat16(f);
    return *reinterpret_cast<ushort*>(&h);
}

// ---------------------------------------------------------------------------
// Prologue 1: node_cat bf16 table [N][64]  (cols 0-31 dim@size_W+size_b, 32-63 orient)
// ---------------------------------------------------------------------------
__global__ __launch_bounds__(256) void k_cat(
    const int* __restrict__ ori, const float* __restrict__ dim,
    const float* __restrict__ otab, const float* __restrict__ sW,
    const float* __restrict__ sb, ushort* __restrict__ cat)
{
    const int t = threadIdx.x;
    const int n = blockIdx.x * 4 + (t >> 6);
    const int c = t & 63;
    float v;
    if (c < 32)
        v = sb[c] + dim[n*3]*sW[c] + dim[n*3+1]*sW[32+c] + dim[n*3+2]*sW[64+c];
    else
        v = otab[ori[n]*32 + (c-32)];
    cat[n*64 + c] = f2bf(v);
}

// ---------------------------------------------------------------------------
// Prologue 2: SW = subj_W@W1a, OW = obj_W@W1c  -> bf16 packed B-fragment layout
// packed idx: ((ks*16+nt)*64 + hi*16+lo)*8 + j  == B[k=ks*32+hi*8+j][n=nt*16+lo]
// ---------------------------------------------------------------------------
__global__ __launch_bounds__(256) void k_fold(
    const float* __restrict__ subj_W, const float* __restrict__ obj_W,
    const float* __restrict__ W1, ushort* __restrict__ SWp, ushort* __restrict__ OWp)
{
    const int idx = blockIdx.x * 256 + threadIdx.x;   // 0..32767
    const int which = idx >> 14;                       // 0=SW 1=OW
    const int e = idx & 16383;
    const int k = e >> 8;                              // 0..63 (cat dim)
    const int n = e & 255;                             // 0..255 (H1 col)
    const float* A = which ? obj_W : subj_W;           // [64][128]
    const float* B = which ? (W1 + 256*256) : W1;      // W1c rows 256.. / W1a rows 0..
    float s = 0.f;
    for (int q = 0; q < 128; ++q) s += A[k*128 + q] * B[q*256 + n];
    const int ks = k >> 5, j = k & 7, hi = (k >> 3) & 3, nt = n >> 4, lo = n & 15;
    ushort* P = which ? OWp : SWp;
    P[((ks*16 + nt)*64 + hi*16 + lo)*8 + j] = f2bf(s);
}

// ---------------------------------------------------------------------------
// Prologue 3: TW1 = trans_W@W1b (fp32 [3][256]), b1p = b1 + all folded biases
// ---------------------------------------------------------------------------
__global__ __launch_bounds__(256) void k_trans(
    const float* __restrict__ trans_W, const float* __restrict__ trans_b,
    const float* __restrict__ subj_b, const float* __restrict__ obj_b,
    const float* __restrict__ W1, const float* __restrict__ b1,
    float* __restrict__ TW1, float* __restrict__ b1p)
{
    const int n = threadIdx.x;                 // 0..255
    float t0 = 0, t1 = 0, t2 = 0, bb = b1[n];
    for (int q = 0; q < 128; ++q) {
        const float wb = W1[(128 + q)*256 + n];
        t0 += trans_W[q]       * wb;
        t1 += trans_W[128 + q] * wb;
        t2 += trans_W[256 + q] * wb;
        bb += trans_b[q] * wb;
        bb += subj_b[q] * W1[q*256 + n];
        bb += obj_b[q]  * W1[(256 + q)*256 + n];
    }
    TW1[n] = t0; TW1[256 + n] = t1; TW1[512 + n] = t2; b1p[n] = bb;
}

// ---------------------------------------------------------------------------
// Prologue 4: pack W2 [256][128] and W3 [128][27]->pad32 into fragment layout
// ---------------------------------------------------------------------------
__global__ __launch_bounds__(256) void k_pack23(
    const float* __restrict__ W2, const float* __restrict__ W3,
    ushort* __restrict__ W2p, ushort* __restrict__ W3p)
{
    const int idx = blockIdx.x * 256 + threadIdx.x;   // 0..36863
    if (idx < 32768) {
        const int g = idx >> 9, k = g >> 3, nt = g & 7;
        const int lane = (idx >> 3) & 63, j = idx & 7;
        W2p[idx] = f2bf(W2[(k*32 + (lane >> 4)*8 + j)*128 + nt*16 + (lane & 15)]);
    } else {
        const int e = idx - 32768;
        const int g = e >> 9, k = g >> 1, nt = g & 1;
        const int lane = (e >> 3) & 63, j = e & 7;
        const int col = nt*16 + (lane & 15);
        const int r = k*32 + (lane >> 4)*8 + j;
        W3p[e] = f2bf((col < NCLS) ? W3[r*NCLS + col] : 0.f);
    }
}

// ---------------------------------------------------------------------------
// Main: fused edge MLP, MFMA. 64 edges/block, 256 thr (4 waves).
// Wave w: GEMM1 cols [w*64,w*64+64), GEMM2 cols [w*32,..), GEMM3 m-tile w.
// LDS h: h1 bf16[64][256] (32KB, XOR-swizzled); h2 bf16[64][128] aliases low 16KB.
// Swizzle: byte_addr ^= (row&7)<<4 on BOTH write and read (T2 / G4).
// ---------------------------------------------------------------------------
__global__ __launch_bounds__(256) void edge_mfma(
    const float* __restrict__ loc, const int* __restrict__ src, const int* __restrict__ dst,
    const ushort* __restrict__ cat, const ushort* __restrict__ SWp, const ushort* __restrict__ OWp,
    const ushort* __restrict__ W2p, const ushort* __restrict__ W3p,
    const float* __restrict__ TW1, const float* __restrict__ b1p,
    const float* __restrict__ b2, const float* __restrict__ b3,
    float* __restrict__ out)
{
    __shared__ ushort h[16384];     // 32 KB
    __shared__ float diffs[64][4];  // 1 KB

    const int t = threadIdx.x, lane = t & 63, w = t >> 6;
    const int lo = lane & 15, hi = lane >> 4;
    const int eb = blockIdx.x * 64;

    if (t < 64) {
        const int s = src[eb + t], d = dst[eb + t];
        diffs[t][0] = loc[s*3]     - loc[d*3];
        diffs[t][1] = loc[s*3 + 1] - loc[d*3 + 1];
        diffs[t][2] = loc[s*3 + 2] - loc[d*3 + 2];
    }
    int sidx[4], didx[4];
#pragma unroll
    for (int m = 0; m < 4; ++m) {
        sidx[m] = src[eb + m*16 + lo];
        didx[m] = dst[eb + m*16 + lo];
    }
    __syncthreads();

    const s8v* catv = (const s8v*)cat;   // 8 chunks of 8 bf16 per 64-col row
    const s8v* swv  = (const s8v*)SWp;
    const s8v* owv  = (const s8v*)OWp;

    // ---- GEMM1: acc1 = cat[src]@SW + cat[dst]@OW  (K=64 each) ----
    f4v acc1[4][4];
#pragma unroll
    for (int m = 0; m < 4; ++m)
#pragma unroll
        for (int nt = 0; nt < 4; ++nt) acc1[m][nt] = (f4v){0.f, 0.f, 0.f, 0.f};

    s8v As[4][2], Ao[4][2];
#pragma unroll
    for (int m = 0; m < 4; ++m) {   // A-frag: row=lo(edge), k = ks*32+hi*8+j
        As[m][0] = catv[sidx[m]*8 + hi];     As[m][1] = catv[sidx[m]*8 + 4 + hi];
        Ao[m][0] = catv[didx[m]*8 + hi];     Ao[m][1] = catv[didx[m]*8 + 4 + hi];
    }
    s8v Bs[2][4], Bo[2][4];
#pragma unroll
    for (int ks = 0; ks < 2; ++ks)
#pragma unroll
        for (int nt = 0; nt < 4; ++nt) {
            Bs[ks][nt] = swv[(ks*16 + w*4 + nt)*64 + lane];
            Bo[ks][nt] = owv[(ks*16 + w*4 + nt)*64 + lane];
        }
#pragma unroll
    for (int m = 0; m < 4; ++m)
#pragma unroll
        for (int nt = 0; nt < 4; ++nt) {
            acc1[m][nt] = __builtin_amdgcn_mfma_f32_16x16x32_bf16(As[m][0], Bs[0][nt], acc1[m][nt], 0, 0, 0);
            acc1[m][nt] = __builtin_amdgcn_mfma_f32_16x16x32_bf16(As[m][1], Bs[1][nt], acc1[m][nt], 0, 0, 0);
            acc1[m][nt] = __builtin_amdgcn_mfma_f32_16x16x32_bf16(Ao[m][0], Bo[0][nt], acc1[m][nt], 0, 0, 0);
            acc1[m][nt] = __builtin_amdgcn_mfma_f32_16x16x32_bf16(Ao[m][1], Bo[1][nt], acc1[m][nt], 0, 0, 0);
        }

    // ---- fold diff@TW1 (fp32 VALU) + bias + relu -> h1 (swizzled bf16) ----
    float tw0[4], tw1[4], tw2[4], bia[4];
#pragma unroll
    for (int nt = 0; nt < 4; ++nt) {
        const int col = w*64 + nt*16 + lo;
        tw0[nt] = TW1[col]; tw1[nt] = TW1[256 + col]; tw2[nt] = TW1[512 + col];
        bia[nt] = b1p[col];
    }
#pragma unroll
    for (int m = 0; m < 4; ++m)
#pragma unroll
        for (int r = 0; r < 4; ++r) {
            const int row = m*16 + hi*4 + r;          // D row = (lane>>4)*4+reg
            const float d0 = diffs[row][0], d1 = diffs[row][1], d2 = diffs[row][2];
#pragma unroll
            for (int nt = 0; nt < 4; ++nt) {
                float v = acc1[m][nt][r] + bia[nt] + d0*tw0[nt] + d1*tw1[nt] + d2*tw2[nt];
                v = fmaxf(v, 0.f);
                const int col = w*64 + nt*16 + lo;    // D col = lane&15
                const int addr = (row*512 + col*2) ^ ((row & 7) << 4);
                *(ushort*)((char*)h + addr) = f2bf(v);
            }
        }
    __syncthreads();

    // ---- GEMM2: h2 = relu(h1 @ W2 + b2)  M=64 N=128 K=256 ----
    f4v acc2[4][2];
#pragma unroll
    for (int m = 0; m < 4; ++m)
#pragma unroll
        for (int nt = 0; nt < 2; ++nt) acc2[m][nt] = (f4v){0.f, 0.f, 0.f, 0.f};

    const s8v* w2v = (const s8v*)W2p;
#pragma unroll
    for (int k = 0; k < 8; ++k) {
        s8v a[4], b[2];
#pragma unroll
        for (int m = 0; m < 4; ++m) {
            const int row = m*16 + lo;
            const int addr = (row*512 + k*64 + hi*16) ^ ((row & 7) << 4);
            a[m] = *(const s8v*)((char*)h + addr);
        }
#pragma unroll
        for (int nt = 0; nt < 2; ++nt) b[nt] = w2v[(k*8 + w*2 + nt)*64 + lane];
#pragma unroll
        for (int m = 0; m < 4; ++m)
#pragma unroll
            for (int nt = 0; nt < 2; ++nt)
                acc2[m][nt] = __builtin_amdgcn_mfma_f32_16x16x32_bf16(a[m], b[nt], acc2[m][nt], 0, 0, 0);
    }
    __syncthreads();   // all h1 reads complete before h2 overwrites region

    {
        float b2v[2];
#pragma unroll
        for (int nt = 0; nt < 2; ++nt) b2v[nt] = b2[w*32 + nt*16 + lo];
#pragma unroll
        for (int m = 0; m < 4; ++m)
#pragma unroll
            for (int nt = 0; nt < 2; ++nt)
#pragma unroll
                for (int r = 0; r < 4; ++r) {
                    const int row = m*16 + hi*4 + r;
                    const int col = w*32 + nt*16 + lo;
                    const float v = fmaxf(acc2[m][nt][r] + b2v[nt], 0.f);
                    const int addr = (row*256 + col*2) ^ ((row & 7) << 4);
                    *(ushort*)((char*)h + addr) = f2bf(v);
                }
    }
    __syncthreads();

    // ---- GEMM3: scores = h2 @ W3(pad32) + b3.  Wave w owns m-tile w. ----
    f4v acc3[2];
#pragma unroll
    for (int nt = 0; nt < 2; ++nt) acc3[nt] = (f4v){0.f, 0.f, 0.f, 0.f};
    const s8v* w3v = (const s8v*)W3p;
#pragma unroll
    for (int k = 0; k < 4; ++k) {
        const int row = w*16 + lo;
        const int addr = (row*256 + k*64 + hi*16) ^ ((row & 7) << 4);
        const s8v a = *(const s8v*)((char*)h + addr);
#pragma unroll
        for (int nt = 0; nt < 2; ++nt) {
            const s8v b = w3v[(k*2 + nt)*64 + lane];
            acc3[nt] = __builtin_amdgcn_mfma_f32_16x16x32_bf16(a, b, acc3[nt], 0, 0, 0);
        }
    }
#pragma unroll
    for (int nt = 0; nt < 2; ++nt) {
        const int col = nt*16 + lo;
        if (col < NCLS) {
            const float bb = b3[col];
#pragma unroll
            for (int r = 0; r < 4; ++r) {
                const int e = eb + w*16 + hi*4 + r;
                out[(size_t)e*NCLS + col] = acc3[nt][r] + bb;
            }
        }
    }
}

// ---------------------------------------------------------------------------
__global__ __launch_bounds__(256) void targets_copy_kernel(
    const int* __restrict__ targets, float* __restrict__ out_tail, int n)
{
    const int i = blockIdx.x * blockDim.x + threadIdx.x;
    if (i < n) out_tail[i] = (float)targets[i];
}

// ---------------------------------------------------------------------------
extern "C" void kernel_launch(void* const* d_in, const int* in_sizes, int n_in,
                              void* d_out, int out_size, void* d_ws, size_t ws_size,
                              hipStream_t stream) {
    const int*   orientation  = (const int*)  d_in[0];
    const float* dimension    = (const float*)d_in[1];
    const float* location     = (const float*)d_in[2];
    const int*   src          = (const int*)  d_in[3];
    const int*   dst          = (const int*)  d_in[4];
    const int*   targets      = (const int*)  d_in[5];
    const float* orient_table = (const float*)d_in[6];
    const float* size_W       = (const float*)d_in[7];
    const float* size_b       = (const float*)d_in[8];
    const float* subj_W       = (const float*)d_in[9];
    // d_in[10] subj_b used below
    const float* obj_W        = (const float*)d_in[11];
    const float* trans_W      = (const float*)d_in[13];
    const float* trans_b      = (const float*)d_in[14];
    const float* W1           = (const float*)d_in[15];
    const float* b1           = (const float*)d_in[16];
    const float* W2           = (const float*)d_in[17];
    const float* b2           = (const float*)d_in[18];
    const float* W3           = (const float*)d_in[19];
    const float* b3           = (const float*)d_in[20];
    const float* subj_b       = (const float*)d_in[10];
    const float* obj_b        = (const float*)d_in[12];

    char* ws = (char*)d_ws;
    ushort* cat = (ushort*)(ws);                 // 6,400,000 B
    ushort* SWp = (ushort*)(ws + 6400000);       // 32,768 B
    ushort* OWp = (ushort*)(ws + 6432768);       // 32,768 B
    ushort* W2p = (ushort*)(ws + 6465536);       // 65,536 B
    ushort* W3p = (ushort*)(ws + 6531072);       //  8,192 B
    float*  TW1 = (float*) (ws + 6539264);       //  3,072 B
    float*  b1p = (float*) (ws + 6542336);       //  1,024 B
    float*  out = (float*)d_out;

    k_cat   <<<12500, 256, 0, stream>>>(orientation, dimension, orient_table,
                                        size_W, size_b, cat);
    k_fold  <<<128,   256, 0, stream>>>(subj_W, obj_W, W1, SWp, OWp);
    k_trans <<<1,     256, 0, stream>>>(trans_W, trans_b, subj_b, obj_b, W1, b1,
                                        TW1, b1p);
    k_pack23<<<144,   256, 0, stream>>>(W2, W3, W2p, W3p);

    edge_mfma<<<N_EDGES / 64, 256, 0, stream>>>(
        location, src, dst, cat, SWp, OWp, W2p, W3p, TW1, b1p, b2, b3, out);

    targets_copy_kernel<<<(N_EDGES + 255) / 256, 256, 0, stream>>>(
        targets, out + (size_t)N_EDGES * NCLS, N_EDGES);
}